// Round 1
// baseline (2081.699 us; speedup 1.0000x reference)
//
#include <hip/hip_runtime.h>
#include <math.h>

#define NH   32      // query heads
#define NKVH 8       // kv heads
#define HD   64      // head dim == wavefront size
#define WIN  256
#define BB   2
#define SS   2048

__device__ __forceinline__ float wave_sum(float x) {
#pragma unroll
    for (int off = 32; off > 0; off >>= 1)
        x += __shfl_xor(x, off, 64);
    return x;
}

// RoPE K into workspace, layout (B, KVH, S, D)
__global__ __launch_bounds__(256) void rope_k_kernel(const float* __restrict__ K,
                                                     float* __restrict__ Kr) {
    int row  = blockIdx.x * 4 + (threadIdx.x >> 6);   // row over B*S*KVH
    int lane = threadIdx.x & 63;
    int kvh = row % NKVH;
    int s   = (row / NKVH) % SS;
    int b   = row / (NKVH * SS);

    float inv = __powf(10000.f, -(float)(2 * (lane & 31)) / (float)HD);
    float sn, cs;
    __sincosf((float)s * inv, &sn, &cs);

    float kv = K[(size_t)(b * SS + s) * (NKVH * HD) + kvh * HD + lane];
    float partner = __shfl(kv, lane ^ 32, 64);
    float krot = kv * cs + ((lane < 32) ? -partner : partner) * sn;

    Kr[((size_t)(b * NKVH + kvh) * SS + s) * HD + lane] = krot;
}

template <bool PREROPE>
__global__ __launch_bounds__(256) void attn_kernel(const float* __restrict__ Q,
                                                   const float* __restrict__ Kany,
                                                   const float* __restrict__ V,
                                                   float* __restrict__ O) {
    int wave = blockIdx.x * 4 + (threadIdx.x >> 6);   // over B*H*S, q fastest
    int lane = threadIdx.x & 63;
    int q  = wave % SS;
    int bh = wave / SS;
    int h  = bh % NH;
    int b  = bh / NH;
    int kvh = h >> 2;            // H/KVH = 4 replicas per kv head

    float inv = __powf(10000.f, -(float)(2 * (lane & 31)) / (float)HD);
    float sn, cs;
    __sincosf((float)q * inv, &sn, &cs);

    float qv = Q[(size_t)(b * SS + q) * (NH * HD) + h * HD + lane];
    float qpart = __shfl(qv, lane ^ 32, 64);
    float qrot = qv * cs + ((lane < 32) ? -qpart : qpart) * sn;
    qrot *= 0.125f;              // fold 1/sqrt(64) into q

    const float* vbase = V + (size_t)b * SS * (NKVH * HD) + kvh * HD;

    float m = -1e30f, l = 0.f, acc = 0.f;
    int k0 = q - WIN; if (k0 < 0) k0 = 0;

    for (int k = k0; k <= q; ++k) {
        float kv;
        if (PREROPE) {
            const float* kbase = Kany + ((size_t)(b * NKVH + kvh) * SS) * HD;
            kv = kbase[(size_t)k * HD + lane];
        } else {
            float kraw = Kany[(size_t)(b * SS + k) * (NKVH * HD) + kvh * HD + lane];
            float kpart = __shfl(kraw, lane ^ 32, 64);
            float ksn, kcs;
            __sincosf((float)k * inv, &ksn, &kcs);
            kv = kraw * kcs + ((lane < 32) ? -kpart : kpart) * ksn;
        }
        float vv = vbase[(size_t)k * (NKVH * HD) + lane];

        float score = wave_sum(qrot * kv);

        float mnew  = fmaxf(m, score);
        float alpha = __expf(m - mnew);
        float p     = __expf(score - mnew);
        l   = l * alpha + p;
        acc = acc * alpha + p * vv;
        m   = mnew;
    }

    O[(((size_t)(b * SS + q) * NH) + h) * HD + lane] = acc / l;
}

extern "C" void kernel_launch(void* const* d_in, const int* in_sizes, int n_in,
                              void* d_out, int out_size, void* d_ws, size_t ws_size,
                              hipStream_t stream) {
    const float* Q = (const float*)d_in[0];
    const float* K = (const float*)d_in[1];
    const float* V = (const float*)d_in[2];
    float* O = (float*)d_out;

    size_t need = (size_t)BB * NKVH * SS * HD * sizeof(float);  // 8 MB

    int attn_blocks = (BB * NH * SS) / 4;   // 4 waves per block, 1 query each

    if (ws_size >= need) {
        float* Kr = (float*)d_ws;
        int rope_blocks = (BB * NKVH * SS) / 4;
        rope_k_kernel<<<rope_blocks, 256, 0, stream>>>(K, Kr);
        attn_kernel<true><<<attn_blocks, 256, 0, stream>>>(Q, Kr, V, O);
    } else {
        attn_kernel<false><<<attn_blocks, 256, 0, stream>>>(Q, K, V, O);
    }
}

// Round 2
// 172.548 us; speedup vs baseline: 12.0645x; 12.0645x over previous
//
#include <hip/hip_runtime.h>
#include <math.h>

#define NH   32
#define NKVH 8
#define HD   64
#define WIN  256
#define BB   2
#define SS   2048
#define QT   16          // queries per wave-tile

typedef short short8 __attribute__((ext_vector_type(8)));
typedef float f32x4  __attribute__((ext_vector_type(4)));

__device__ __forceinline__ ushort f2bf(float x) {
    union { float f; unsigned u; } v; v.f = x;
    unsigned u = v.u + 0x7FFF + ((v.u >> 16) & 1);   // RNE
    return (ushort)(u >> 16);
}

// ---------- pre-pass: RoPE K -> bf16, layout [b][kvh][s][d] ----------
__global__ __launch_bounds__(256) void rope_k_bf16(const float* __restrict__ K,
                                                   ushort* __restrict__ Kr) {
    int row  = blockIdx.x * 4 + (threadIdx.x >> 6);   // over B*S*KVH
    int lane = threadIdx.x & 63;
    int kvh = row % NKVH;
    int s   = (row / NKVH) % SS;
    int b   = row / (NKVH * SS);

    float inv = __powf(10000.f, -(float)(lane & 31) * (1.f / 32.f));
    float sn, cs;
    __sincosf((float)s * inv, &sn, &cs);

    float kv = K[(size_t)(b * SS + s) * (NKVH * HD) + kvh * HD + lane];
    float partner = __shfl(kv, lane ^ 32, 64);
    float krot = kv * cs + ((lane < 32) ? -partner : partner) * sn;

    Kr[((size_t)(b * NKVH + kvh) * SS + s) * HD + lane] = f2bf(krot);
}

// ---------- pre-pass: V -> bf16 transposed, layout [b][kvh][d][s] ----------
__global__ __launch_bounds__(256) void transpose_v_bf16(const float* __restrict__ V,
                                                        ushort* __restrict__ Vt) {
    __shared__ ushort tile[64][65];
    int bidx = blockIdx.x;                 // over B*KVH*(SS/64)
    int s0   = (bidx & 31) * 64;
    int kvh  = (bidx >> 5) & 7;
    int b    = bidx >> 8;
    int t    = threadIdx.x;
    int d    = t & 63, g = t >> 6;
#pragma unroll
    for (int i = 0; i < 16; ++i) {
        int sl = g * 16 + i;
        tile[sl][d] = f2bf(V[(size_t)(b * SS + s0 + sl) * (NKVH * HD) + kvh * HD + d]);
    }
    __syncthreads();
#pragma unroll
    for (int i = 0; i < 16; ++i) {
        int dr = g * 16 + i;
        Vt[((size_t)(b * NKVH + kvh) * HD + dr) * SS + s0 + d] = tile[d][dr];
    }
}

// ---------- main: MFMA flash attention, 1 wave per 16-query tile ----------
__global__ __launch_bounds__(256) void attn_mfma(const float* __restrict__ Q,
                                                 const ushort* __restrict__ Kr,
                                                 const ushort* __restrict__ Vt,
                                                 float* __restrict__ O) {
    __shared__ ushort Pl[4][QT][40];       // stride 40 bf16 = 80B -> 16B-aligned b128 reads
    int wv   = threadIdx.x >> 6;
    int lane = threadIdx.x & 63;
    int tile = blockIdx.x * 4 + wv;
    int q0   = (tile & 127) * QT;          // SS/QT = 128 tiles along S
    int h    = (tile >> 7) & 31;
    int b    = tile >> 12;
    int kvh  = h >> 2;
    int lo16 = lane & 15, quad = lane >> 4;

    // ---- Q tile load + RoPE + scale -> bf16 A-frags (dims 0-31, 32-63) ----
    int qi = q0 + lo16;
    const float* qrow = Q + (size_t)(b * SS + qi) * (NH * HD) + h * HD;
    float q0v[8], q1v[8];
    *(float4*)(q0v)     = *(const float4*)(qrow + quad * 8);
    *(float4*)(q0v + 4) = *(const float4*)(qrow + quad * 8 + 4);
    *(float4*)(q1v)     = *(const float4*)(qrow + 32 + quad * 8);
    *(float4*)(q1v + 4) = *(const float4*)(qrow + 32 + quad * 8 + 4);
    short8 aq0, aq1;
#pragma unroll
    for (int j = 0; j < 8; ++j) {
        int d = quad * 8 + j;
        float invf = __powf(10000.f, -(float)d * (1.f / 32.f));
        float sn, cs;
        __sincosf((float)qi * invf, &sn, &cs);
        aq0[j] = (short)f2bf((q0v[j] * cs - q1v[j] * sn) * 0.125f);
        aq1[j] = (short)f2bf((q1v[j] * cs + q0v[j] * sn) * 0.125f);
    }

    const ushort* kbase = Kr + (size_t)(b * NKVH + kvh) * SS * HD;
    const ushort* vbase = Vt + (size_t)(b * NKVH + kvh) * HD * SS;

    f32x4 acc0 = {0.f, 0.f, 0.f, 0.f}, acc1 = acc0, acc2 = acc0, acc3 = acc0;
    f32x4 psum = {0.f, 0.f, 0.f, 0.f};

    int klo = q0 - WIN; if (klo < 0) klo = 0;
    int khi = q0 + QT - 1;
    int qrow0 = q0 + quad * 4;

    for (int kb = klo; kb <= khi; kb += 32) {
        // ---- K fragments (B-operand): 2 key sub-tiles x 2 dim halves ----
        int key0 = kb + lo16;       int key0c = key0 < SS ? key0 : SS - 1;
        int key1 = key0 + 16;       int key1c = key1 < SS ? key1 : SS - 1;
        short8 kf00 = *(const short8*)(kbase + (size_t)key0c * HD + quad * 8);
        short8 kf01 = *(const short8*)(kbase + (size_t)key0c * HD + 32 + quad * 8);
        short8 kf10 = *(const short8*)(kbase + (size_t)key1c * HD + quad * 8);
        short8 kf11 = *(const short8*)(kbase + (size_t)key1c * HD + 32 + quad * 8);

        f32x4 z = {0.f, 0.f, 0.f, 0.f};
        f32x4 s0 = __builtin_amdgcn_mfma_f32_16x16x32_bf16(aq0, kf00, z, 0, 0, 0);
        s0       = __builtin_amdgcn_mfma_f32_16x16x32_bf16(aq1, kf01, s0, 0, 0, 0);
        f32x4 s1 = __builtin_amdgcn_mfma_f32_16x16x32_bf16(aq0, kf10, z, 0, 0, 0);
        s1       = __builtin_amdgcn_mfma_f32_16x16x32_bf16(aq1, kf11, s1, 0, 0, 0);

        // ---- mask + exp (no max subtraction: |s| <= ~20, fp32-safe) ----
        f32x4 p0, p1;
#pragma unroll
        for (int r = 0; r < 4; ++r) {
            int qq = qrow0 + r;
            p0[r] = __expf(((key0 <= qq) && (key0 >= qq - WIN)) ? s0[r] : -1e30f);
            p1[r] = __expf(((key1 <= qq) && (key1 >= qq - WIN)) ? s1[r] : -1e30f);
            psum[r] += p0[r] + p1[r];
        }

        // ---- P relayout C->A via per-wave LDS round-trip ----
#pragma unroll
        for (int r = 0; r < 4; ++r) {
            Pl[wv][quad * 4 + r][lo16]      = f2bf(p0[r]);
            Pl[wv][quad * 4 + r][16 + lo16] = f2bf(p1[r]);
        }
        __asm__ volatile("s_waitcnt lgkmcnt(0)" ::: "memory");
        short8 ap = *(const short8*)(&Pl[wv][lo16][quad * 8]);

        // ---- V fragments (B-operand) + PV MFMAs ----
        int sb = kb + quad * 8; if (sb > SS - 8) sb = SS - 8;   // clamp; clamped keys have P=0
        short8 vf0 = *(const short8*)(vbase + (size_t)(0 * 16 + lo16) * SS + sb);
        short8 vf1 = *(const short8*)(vbase + (size_t)(1 * 16 + lo16) * SS + sb);
        short8 vf2 = *(const short8*)(vbase + (size_t)(2 * 16 + lo16) * SS + sb);
        short8 vf3 = *(const short8*)(vbase + (size_t)(3 * 16 + lo16) * SS + sb);

        acc0 = __builtin_amdgcn_mfma_f32_16x16x32_bf16(ap, vf0, acc0, 0, 0, 0);
        acc1 = __builtin_amdgcn_mfma_f32_16x16x32_bf16(ap, vf1, acc1, 0, 0, 0);
        acc2 = __builtin_amdgcn_mfma_f32_16x16x32_bf16(ap, vf2, acc2, 0, 0, 0);
        acc3 = __builtin_amdgcn_mfma_f32_16x16x32_bf16(ap, vf3, acc3, 0, 0, 0);
        __asm__ volatile("" ::: "memory");   // keep next iter's LDS writes after this read
    }

    // ---- final row-sum butterfly (within 16-lane groups) + store ----
#pragma unroll
    for (int off = 1; off < 16; off <<= 1) {
#pragma unroll
        for (int r = 0; r < 4; ++r) psum[r] += __shfl_xor(psum[r], off, 64);
    }
    f32x4 inv;
#pragma unroll
    for (int r = 0; r < 4; ++r) inv[r] = 1.f / psum[r];

#pragma unroll
    for (int r = 0; r < 4; ++r) {
        size_t orow = ((size_t)(b * SS + qrow0 + r) * NH + h) * HD;
        O[orow + 0 * 16 + lo16] = acc0[r] * inv[r];
        O[orow + 1 * 16 + lo16] = acc1[r] * inv[r];
        O[orow + 2 * 16 + lo16] = acc2[r] * inv[r];
        O[orow + 3 * 16 + lo16] = acc3[r] * inv[r];
    }
}

// ---------- fallback (no workspace): round-1 scalar kernel ----------
__device__ __forceinline__ float wave_sum(float x) {
#pragma unroll
    for (int off = 32; off > 0; off >>= 1) x += __shfl_xor(x, off, 64);
    return x;
}

__global__ __launch_bounds__(256) void attn_scalar(const float* __restrict__ Q,
                                                   const float* __restrict__ K,
                                                   const float* __restrict__ V,
                                                   float* __restrict__ O) {
    int wave = blockIdx.x * 4 + (threadIdx.x >> 6);
    int lane = threadIdx.x & 63;
    int q  = wave % SS;
    int bh = wave / SS;
    int h  = bh % NH;
    int b  = bh / NH;
    int kvh = h >> 2;

    float inv = __powf(10000.f, -(float)(lane & 31) * (1.f / 32.f));
    float sn, cs;
    __sincosf((float)q * inv, &sn, &cs);

    float qv = Q[(size_t)(b * SS + q) * (NH * HD) + h * HD + lane];
    float qpart = __shfl(qv, lane ^ 32, 64);
    float qrot = (qv * cs + ((lane < 32) ? -qpart : qpart) * sn) * 0.125f;

    const float* vbase = V + (size_t)b * SS * (NKVH * HD) + kvh * HD;
    float m = -1e30f, l = 0.f, acc = 0.f;
    int k0 = q - WIN; if (k0 < 0) k0 = 0;
    for (int k = k0; k <= q; ++k) {
        float kraw = K[(size_t)(b * SS + k) * (NKVH * HD) + kvh * HD + lane];
        float kpart = __shfl(kraw, lane ^ 32, 64);
        float ksn, kcs;
        __sincosf((float)k * inv, &ksn, &kcs);
        float kv = kraw * kcs + ((lane < 32) ? -kpart : kpart) * ksn;
        float vv = vbase[(size_t)k * (NKVH * HD) + lane];
        float score = wave_sum(qrot * kv);
        float mnew  = fmaxf(m, score);
        float alpha = __expf(m - mnew);
        float p     = __expf(score - mnew);
        l   = l * alpha + p;
        acc = acc * alpha + p * vv;
        m   = mnew;
    }
    O[(((size_t)(b * SS + q) * NH) + h) * HD + lane] = acc / l;
}

extern "C" void kernel_launch(void* const* d_in, const int* in_sizes, int n_in,
                              void* d_out, int out_size, void* d_ws, size_t ws_size,
                              hipStream_t stream) {
    const float* Q = (const float*)d_in[0];
    const float* K = (const float*)d_in[1];
    const float* V = (const float*)d_in[2];
    float* O = (float*)d_out;

    size_t kv_elems = (size_t)BB * NKVH * SS * HD;        // 2M elements
    size_t need = 2 * kv_elems * sizeof(ushort);          // 8 MB

    if (ws_size >= need) {
        ushort* Kr = (ushort*)d_ws;
        ushort* Vt = Kr + kv_elems;
        rope_k_bf16<<<(BB * NKVH * SS) / 4, 256, 0, stream>>>(K, Kr);
        transpose_v_bf16<<<BB * NKVH * (SS / 64), 256, 0, stream>>>(V, Vt);
        int tiles = BB * NH * (SS / QT);                  // 8192 waves
        attn_mfma<<<tiles / 4, 256, 0, stream>>>(Q, Kr, Vt, O);
    } else {
        attn_scalar<<<(BB * NH * SS) / 4, 256, 0, stream>>>(Q, K, V, O);
    }
}

// Round 3
// 133.706 us; speedup vs baseline: 15.5692x; 1.2905x over previous
//
#include <hip/hip_runtime.h>
#include <math.h>

#define NH   32
#define NKVH 8
#define HD   64
#define WIN  256
#define BB   2
#define SS   2048

typedef short short8 __attribute__((ext_vector_type(8)));
typedef float f32x4  __attribute__((ext_vector_type(4)));

__device__ __forceinline__ ushort f2bf(float x) {
    union { float f; unsigned u; } v; v.f = x;
    unsigned u = v.u + 0x7FFF + ((v.u >> 16) & 1);   // RNE
    return (ushort)(u >> 16);
}

// ---- fused pre-pass: RoPE K -> bf16 [b][kvh][s][d]; V -> bf16 [b][kvh][d][s] ----
__global__ __launch_bounds__(256) void prep_kv(const float* __restrict__ K,
                                               const float* __restrict__ V,
                                               ushort* __restrict__ Kr,
                                               ushort* __restrict__ Vt) {
    __shared__ ushort tile[64][65];
    int bidx = blockIdx.x;                // (b, kvh, sblk): 2*8*32
    int s0  = (bidx & 31) * 64;
    int kvh = (bidx >> 5) & 7;
    int b   = bidx >> 8;
    int d   = threadIdx.x & 63, g = threadIdx.x >> 6;

    float inv = __powf(10000.f, -(float)(d & 31) * (1.f / 32.f));
#pragma unroll
    for (int i = 0; i < 16; ++i) {
        int s = s0 + g * 16 + i;
        float kv = K[(size_t)(b * SS + s) * (NKVH * HD) + kvh * HD + d];
        float partner = __shfl(kv, d ^ 32, 64);
        float sn, cs;
        __sincosf((float)s * inv, &sn, &cs);
        float krot = kv * cs + ((d < 32) ? -partner : partner) * sn;
        Kr[((size_t)(b * NKVH + kvh) * SS + s) * HD + d] = f2bf(krot);
    }
#pragma unroll
    for (int i = 0; i < 16; ++i) {
        int sl = g * 16 + i;
        tile[sl][d] = f2bf(V[(size_t)(b * SS + s0 + sl) * (NKVH * HD) + kvh * HD + d]);
    }
    __syncthreads();
#pragma unroll
    for (int i = 0; i < 16; ++i) {
        int dr = g * 16 + i;
        Vt[((size_t)(b * NKVH + kvh) * HD + dr) * SS + s0 + d] = tile[d][dr];
    }
}

// ---- main: 1 wave = 32 queries (2 MFMA tiles); block = 4 head-replicas of one kvh ----
__global__ __launch_bounds__(256, 4) void attn_mfma(const float* __restrict__ Q,
                                                    const ushort* __restrict__ Kr,
                                                    const ushort* __restrict__ Vt,
                                                    float* __restrict__ O) {
    __shared__ ushort Pl[4][2][2][16][40];   // [wave][dbuf][tile][query][key(32)+pad]
    const int wv = threadIdx.x >> 6, lane = threadIdx.x & 63;
    const int lo16 = lane & 15, quad = lane >> 4;
    const int bidx = blockIdx.x;             // (b, kvh, qblk): 2*8*64
    const int qblk = bidx & 63;
    const int kvh  = (bidx >> 6) & 7;
    const int b    = bidx >> 9;
    const int h    = kvh * 4 + wv;
    const int q0   = qblk * 32;

    float invf[8];
#pragma unroll
    for (int j = 0; j < 8; ++j)
        invf[j] = __powf(10000.f, -(float)(quad * 8 + j) * (1.f / 32.f));

    // Q load + RoPE + scale -> A-frag-shaped regs (used as MFMA B operand)
    short8 aq[2][2];
#pragma unroll
    for (int t = 0; t < 2; ++t) {
        int qi = q0 + t * 16 + lo16;
        const float* qrow = Q + (size_t)(b * SS + qi) * (NH * HD) + h * HD;
        float lo[8], hi[8];
        *(float4*)(lo)     = *(const float4*)(qrow + quad * 8);
        *(float4*)(lo + 4) = *(const float4*)(qrow + quad * 8 + 4);
        *(float4*)(hi)     = *(const float4*)(qrow + 32 + quad * 8);
        *(float4*)(hi + 4) = *(const float4*)(qrow + 32 + quad * 8 + 4);
#pragma unroll
        for (int j = 0; j < 8; ++j) {
            float sn, cs;
            __sincosf((float)qi * invf[j], &sn, &cs);
            aq[t][0][j] = (short)f2bf((lo[j] * cs - hi[j] * sn) * 0.125f);
            aq[t][1][j] = (short)f2bf((hi[j] * cs + lo[j] * sn) * 0.125f);
        }
    }

    const ushort* kbase = Kr + (size_t)(b * NKVH + kvh) * SS * HD;
    const ushort* vbase = Vt + (size_t)(b * NKVH + kvh) * HD * SS;

    f32x4 acc[2][4];
#pragma unroll
    for (int t = 0; t < 2; ++t)
#pragma unroll
        for (int i = 0; i < 4; ++i) acc[t][i] = (f32x4){0.f, 0.f, 0.f, 0.f};
    float psum[2] = {0.f, 0.f};

    int klo = q0 - WIN; if (klo < 0) klo = 0;
    const int khi = q0 + 31;

    short8 kcur[4], knxt[4];
    {
        int key0 = klo + lo16, key1 = klo + 16 + lo16;
        kcur[0] = *(const short8*)(kbase + (size_t)key0 * HD + quad * 8);
        kcur[1] = *(const short8*)(kbase + (size_t)key0 * HD + 32 + quad * 8);
        kcur[2] = *(const short8*)(kbase + (size_t)key1 * HD + quad * 8);
        kcur[3] = *(const short8*)(kbase + (size_t)key1 * HD + 32 + quad * 8);
    }

    int buf = 0;
    for (int kb = klo; kb <= khi; kb += 32, buf ^= 1) {
        const f32x4 z = {0.f, 0.f, 0.f, 0.f};
        // S^T = K·Q^T : C[row=key(quad*4+r)][col=query(lo16)]
        f32x4 s00 = __builtin_amdgcn_mfma_f32_16x16x32_bf16(kcur[0], aq[0][0], z,   0, 0, 0);
        s00       = __builtin_amdgcn_mfma_f32_16x16x32_bf16(kcur[1], aq[0][1], s00, 0, 0, 0);
        f32x4 s01 = __builtin_amdgcn_mfma_f32_16x16x32_bf16(kcur[2], aq[0][0], z,   0, 0, 0);
        s01       = __builtin_amdgcn_mfma_f32_16x16x32_bf16(kcur[3], aq[0][1], s01, 0, 0, 0);
        f32x4 s10 = __builtin_amdgcn_mfma_f32_16x16x32_bf16(kcur[0], aq[1][0], z,   0, 0, 0);
        s10       = __builtin_amdgcn_mfma_f32_16x16x32_bf16(kcur[1], aq[1][1], s10, 0, 0, 0);
        f32x4 s11 = __builtin_amdgcn_mfma_f32_16x16x32_bf16(kcur[2], aq[1][0], z,   0, 0, 0);
        s11       = __builtin_amdgcn_mfma_f32_16x16x32_bf16(kcur[3], aq[1][1], s11, 0, 0, 0);

#pragma unroll
        for (int t = 0; t < 2; ++t) {
            const f32x4 sa = t ? s10 : s00;
            const f32x4 sb = t ? s11 : s01;
            const int qtmin = q0 + t * 16;
            const int myq   = qtmin + lo16;
            float p[8];
            if ((kb + 31 > qtmin) || (kb < qtmin + 15 - WIN)) {   // boundary chunk: mask
#pragma unroll
                for (int r = 0; r < 4; ++r) {
                    int key0 = kb + quad * 4 + r;
                    int key1 = key0 + 16;
                    p[r]     = (key0 <= myq && key0 >= myq - WIN) ? __expf(sa[r]) : 0.f;
                    p[4 + r] = (key1 <= myq && key1 >= myq - WIN) ? __expf(sb[r]) : 0.f;
                }
            } else {                                              // interior: no mask
#pragma unroll
                for (int r = 0; r < 4; ++r) { p[r] = __expf(sa[r]); p[4 + r] = __expf(sb[r]); }
            }
            psum[t] += ((p[0] + p[1]) + (p[2] + p[3])) + ((p[4] + p[5]) + (p[6] + p[7]));
            ushort4 u0 = make_ushort4(f2bf(p[0]), f2bf(p[1]), f2bf(p[2]), f2bf(p[3]));
            ushort4 u1 = make_ushort4(f2bf(p[4]), f2bf(p[5]), f2bf(p[6]), f2bf(p[7]));
            *(ushort4*)&Pl[wv][buf][t][lo16][quad * 4]      = u0;   // keys kb+quad*4..+3
            *(ushort4*)&Pl[wv][buf][t][lo16][16 + quad * 4] = u1;   // keys kb+16+quad*4..+3
        }

        // prefetch next K chunk (clamped; extra chunk harmless)
        {
            int key0 = kb + 32 + lo16; if (key0 > SS - 1) key0 = SS - 1;
            int key1 = key0 + 16;      if (key1 > SS - 1) key1 = SS - 1;
            knxt[0] = *(const short8*)(kbase + (size_t)key0 * HD + quad * 8);
            knxt[1] = *(const short8*)(kbase + (size_t)key0 * HD + 32 + quad * 8);
            knxt[2] = *(const short8*)(kbase + (size_t)key1 * HD + quad * 8);
            knxt[3] = *(const short8*)(kbase + (size_t)key1 * HD + 32 + quad * 8);
        }
        // current V chunk (clamped; clamped keys have P=0)
        short8 vf[4];
        {
            int sb2 = kb + quad * 8; if (sb2 > SS - 8) sb2 = SS - 8;
#pragma unroll
            for (int i = 0; i < 4; ++i)
                vf[i] = *(const short8*)(vbase + (size_t)(i * 16 + lo16) * SS + sb2);
        }

        __asm__ volatile("s_waitcnt lgkmcnt(0)" ::: "memory");
        short8 ap0 = *(const short8*)&Pl[wv][buf][0][lo16][quad * 8];
        short8 ap1 = *(const short8*)&Pl[wv][buf][1][lo16][quad * 8];

#pragma unroll
        for (int i = 0; i < 4; ++i)
            acc[0][i] = __builtin_amdgcn_mfma_f32_16x16x32_bf16(ap0, vf[i], acc[0][i], 0, 0, 0);
#pragma unroll
        for (int i = 0; i < 4; ++i)
            acc[1][i] = __builtin_amdgcn_mfma_f32_16x16x32_bf16(ap1, vf[i], acc[1][i], 0, 0, 0);

#pragma unroll
        for (int i = 0; i < 4; ++i) kcur[i] = knxt[i];
    }

#pragma unroll
    for (int t = 0; t < 2; ++t) {
        float ps = psum[t];
        ps += __shfl_xor(ps, 16, 64);
        ps += __shfl_xor(ps, 32, 64);        // all lanes: total for query lo16
#pragma unroll
        for (int r = 0; r < 4; ++r) {
            float invr = 1.f / __shfl(ps, quad * 4 + r, 16);
            int qr = q0 + t * 16 + quad * 4 + r;
            size_t orow = ((size_t)(b * SS + qr) * NH + h) * HD;
            O[orow + 0 * 16 + lo16] = acc[t][0][r] * invr;
            O[orow + 1 * 16 + lo16] = acc[t][1][r] * invr;
            O[orow + 2 * 16 + lo16] = acc[t][2][r] * invr;
            O[orow + 3 * 16 + lo16] = acc[t][3][r] * invr;
        }
    }
}

// ---------- fallback (no workspace): round-1 scalar kernel ----------
__device__ __forceinline__ float wave_sum(float x) {
#pragma unroll
    for (int off = 32; off > 0; off >>= 1) x += __shfl_xor(x, off, 64);
    return x;
}

__global__ __launch_bounds__(256) void attn_scalar(const float* __restrict__ Q,
                                                   const float* __restrict__ K,
                                                   const float* __restrict__ V,
                                                   float* __restrict__ O) {
    int wave = blockIdx.x * 4 + (threadIdx.x >> 6);
    int lane = threadIdx.x & 63;
    int q  = wave % SS;
    int bh = wave / SS;
    int h  = bh % NH;
    int b  = bh / NH;
    int kvh = h >> 2;

    float inv = __powf(10000.f, -(float)(lane & 31) * (1.f / 32.f));
    float sn, cs;
    __sincosf((float)q * inv, &sn, &cs);

    float qv = Q[(size_t)(b * SS + q) * (NH * HD) + h * HD + lane];
    float qpart = __shfl(qv, lane ^ 32, 64);
    float qrot = (qv * cs + ((lane < 32) ? -qpart : qpart) * sn) * 0.125f;

    const float* vbase = V + (size_t)b * SS * (NKVH * HD) + kvh * HD;
    float m = -1e30f, l = 0.f, acc = 0.f;
    int k0 = q - WIN; if (k0 < 0) k0 = 0;
    for (int k = k0; k <= q; ++k) {
        float kraw = K[(size_t)(b * SS + k) * (NKVH * HD) + kvh * HD + lane];
        float kpart = __shfl(kraw, lane ^ 32, 64);
        float ksn, kcs;
        __sincosf((float)k * inv, &ksn, &kcs);
        float kv = kraw * kcs + ((lane < 32) ? -kpart : kpart) * ksn;
        float vv = vbase[(size_t)k * (NKVH * HD) + lane];
        float score = wave_sum(qrot * kv);
        float mnew  = fmaxf(m, score);
        float alpha = __expf(m - mnew);
        float p     = __expf(score - mnew);
        l   = l * alpha + p;
        acc = acc * alpha + p * vv;
        m   = mnew;
    }
    O[(((size_t)(b * SS + q) * NH) + h) * HD + lane] = acc / l;
}

extern "C" void kernel_launch(void* const* d_in, const int* in_sizes, int n_in,
                              void* d_out, int out_size, void* d_ws, size_t ws_size,
                              hipStream_t stream) {
    const float* Q = (const float*)d_in[0];
    const float* K = (const float*)d_in[1];
    const float* V = (const float*)d_in[2];
    float* O = (float*)d_out;

    size_t kv_elems = (size_t)BB * NKVH * SS * HD;   // 2M elements
    size_t need = 2 * kv_elems * sizeof(ushort);     // 8 MB

    if (ws_size >= need) {
        ushort* Kr = (ushort*)d_ws;
        ushort* Vt = Kr + kv_elems;
        prep_kv<<<BB * NKVH * (SS / 64), 256, 0, stream>>>(K, V, Kr, Vt);
        attn_mfma<<<BB * NKVH * (SS / 32), 256, 0, stream>>>(Q, Kr, Vt, O);
    } else {
        attn_scalar<<<(BB * NH * SS) / 4, 256, 0, stream>>>(Q, K, V, O);
    }
}